// Round 1
// baseline (551.355 us; speedup 1.0000x reference)
//
#include <hip/hip_runtime.h>

// BLOOM attention block on MI355X (gfx950).
// All GEMM-shaped compute in bf16 MFMA (16x16x32) with fp32 accumulation.
// Workspace layout (requires ws_size >= 160 MiB):
//   [0)        q_bf   [32][2048][128] bf16   16 MiB
//   [16M)      k_bf   [32][2048][128] bf16   16 MiB
//   [32M)      v_t    [32][128][2048] bf16   16 MiB  (V transposed: [head][d][s])
//   [48M)      hid_bf [2048][4096]    bf16   16 MiB
//   [64M)      wbig:  Wqkv_bf [12288][4096] (96 MiB), later reused as
//              Wd_bf [4096][4096] (32 MiB) + ctx_bf [2048][4096] (16 MiB)

#define SEQL 2048
#define HIDN 4096
#define NHEAD 32
#define HDIM 128
#define H3 12288

typedef __bf16 bf16x8 __attribute__((ext_vector_type(8)));
typedef float f32x4 __attribute__((ext_vector_type(4)));
typedef unsigned short u16x8 __attribute__((ext_vector_type(8)));

__device__ __forceinline__ unsigned short f2bf(float f) {
  union { float f; unsigned u; } v; v.f = f;
  return (unsigned short)((v.u + 0x7FFFu + ((v.u >> 16) & 1u)) >> 16);
}

__global__ __launch_bounds__(256) void cvt_f32_bf16(
    const float* __restrict__ in, unsigned short* __restrict__ out, long long n) {
  long long i = ((long long)blockIdx.x * blockDim.x + threadIdx.x) * 8;
  long long stride = (long long)gridDim.x * blockDim.x * 8;
  for (; i < n; i += stride) {
    float4 a = *(const float4*)(in + i);
    float4 b = *(const float4*)(in + i + 4);
    u16x8 o;
    o[0] = f2bf(a.x); o[1] = f2bf(a.y); o[2] = f2bf(a.z); o[3] = f2bf(a.w);
    o[4] = f2bf(b.x); o[5] = f2bf(b.y); o[6] = f2bf(b.z); o[7] = f2bf(b.w);
    *(u16x8*)(out + i) = o;
  }
}

// C[M,N] = A[M,K] * B[N,K]^T (+ epilogue). A,B bf16 (ushort bits).
// 128x128 tile, BK=64, 4 waves (2x2 of 64x64), 16x16x32 MFMA, 4x4 frags/wave.
// LDS tiles [128 rows][64 cols] bf16 with XOR swizzle: byte ^= (row&7)<<4.
// EPI==0: QKV scatter epilogue (bias + write q/k/v_t as bf16).
// EPI==1: out = acc + bias[col] + residual[row*N+col], fp32.
template <int EPI>
__global__ __launch_bounds__(256) void gemm_nt(
    const unsigned short* __restrict__ A, const unsigned short* __restrict__ B,
    int M, int N, int K,
    const float* __restrict__ bias, const float* __restrict__ residual,
    float* __restrict__ outf,
    unsigned short* __restrict__ q_bf, unsigned short* __restrict__ k_bf,
    unsigned short* __restrict__ v_t) {
  __shared__ unsigned short As[128 * 64];  // 16 KiB
  __shared__ unsigned short Bs[128 * 64];  // 16 KiB

  const int tid = threadIdx.x;
  const int l = tid & 63;
  const int w = tid >> 6;
  const int wr = (w >> 1) * 64;   // wave row offset in tile
  const int wc = (w & 1) * 64;    // wave col offset in tile
  const int tm0 = blockIdx.y * 128;
  const int tn0 = blockIdx.x * 128;

  const int g8 = tid & 7;        // staging: 16B group in row (8 per 128B row)
  const int srow = tid >> 3;     // staging: row 0..31 (4 passes)

  f32x4 acc[4][4] = {};

  for (int kt = 0; kt < K; kt += 64) {
    __syncthreads();
#pragma unroll
    for (int p = 0; p < 4; ++p) {
      int row = srow + p * 32;
      u16x8 va = *(const u16x8*)&A[(long long)(tm0 + row) * K + kt + g8 * 8];
      *(u16x8*)((char*)As + row * 128 + ((g8 * 16) ^ ((row & 7) << 4))) = va;
      u16x8 vb = *(const u16x8*)&B[(long long)(tn0 + row) * K + kt + g8 * 8];
      *(u16x8*)((char*)Bs + row * 128 + ((g8 * 16) ^ ((row & 7) << 4))) = vb;
    }
    __syncthreads();
#pragma unroll
    for (int kk = 0; kk < 2; ++kk) {
      const int colb = kk * 64 + (l >> 4) * 16;  // byte offset in row
      bf16x8 af[4], bfr[4];
#pragma unroll
      for (int m = 0; m < 4; ++m) {
        int row = wr + m * 16 + (l & 15);
        af[m] = *(const bf16x8*)((char*)As + row * 128 + (colb ^ ((row & 7) << 4)));
      }
#pragma unroll
      for (int n = 0; n < 4; ++n) {
        int row = wc + n * 16 + (l & 15);
        bfr[n] = *(const bf16x8*)((char*)Bs + row * 128 + (colb ^ ((row & 7) << 4)));
      }
#pragma unroll
      for (int m = 0; m < 4; ++m)
#pragma unroll
        for (int n = 0; n < 4; ++n)
          acc[m][n] = __builtin_amdgcn_mfma_f32_16x16x32_bf16(af[m], bfr[n], acc[m][n], 0, 0, 0);
    }
  }

  // Epilogue. D layout: col = lane&15, row = (lane>>4)*4 + reg (m89-verified).
#pragma unroll
  for (int m = 0; m < 4; ++m) {
#pragma unroll
    for (int n = 0; n < 4; ++n) {
      const int col = tn0 + wc + n * 16 + (l & 15);
      const float bv = bias[col];
#pragma unroll
      for (int r = 0; r < 4; ++r) {
        const int rowg = tm0 + wr + m * 16 + (l >> 4) * 4 + r;
        float v = acc[m][n][r] + bv;
        if (EPI == 0) {
          // fused[s, head*384 + which*128 + d]
          const int head = col / 384;
          const int rem = col - head * 384;
          const int which = rem >> 7;
          const int d = rem & 127;
          const unsigned short bv16 = f2bf(v);
          if (which == 0)
            q_bf[(long long)(head * SEQL + rowg) * HDIM + d] = bv16;
          else if (which == 1)
            k_bf[(long long)(head * SEQL + rowg) * HDIM + d] = bv16;
          else
            v_t[(long long)(head * HDIM + d) * SEQL + rowg] = bv16;
        } else {
          const long long idx = (long long)rowg * N + col;
          outf[idx] = v + residual[idx];
        }
      }
    }
  }
}

// Flash attention with alibi + causal mask.
// Block: one head x 64 q rows. 4 waves, each owns 16 q rows.
// KV tiles of 64. K staged [64][128], V^T staged [128][64], both XOR-swizzled.
__global__ __launch_bounds__(256) void attn_fwd(
    const unsigned short* __restrict__ q_bf, const unsigned short* __restrict__ k_bf,
    const unsigned short* __restrict__ v_t, const float* __restrict__ alibi,
    unsigned short* __restrict__ ctx_bf) {
  __shared__ unsigned short Ks[64 * 128];   // 16 KiB
  __shared__ unsigned short Vs[128 * 64];   // 16 KiB  (rows = d, cols = kv)
  __shared__ unsigned short Ps[4][16 * 64]; // 8 KiB   (per-wave P tile)
  __shared__ float Al[SEQL];                // 8 KiB   (alibi row for this head)

  const int tid = threadIdx.x;
  const int l = tid & 63;
  const int w = tid >> 6;
  const int h = blockIdx.x;
  const int qt = blockIdx.y * 64;
  const int qw = qt + w * 16;  // this wave's q-row base

  for (int i = tid; i < SEQL; i += 256) Al[i] = alibi[h * SEQL + i];

  // Q fragments in registers: lane l holds row qw+(l&15), cols kk*32+(l>>4)*8..+7
  bf16x8 qf[4];
  {
    const unsigned short* qp =
        &q_bf[(long long)(h * SEQL + qw + (l & 15)) * HDIM + (l >> 4) * 8];
#pragma unroll
    for (int kk = 0; kk < 4; ++kk) qf[kk] = *(const bf16x8*)(qp + kk * 32);
  }

  f32x4 oacc[8] = {};
  float mrun[4] = {-__builtin_inff(), -__builtin_inff(), -__builtin_inff(), -__builtin_inff()};
  float lrun[4] = {0.f, 0.f, 0.f, 0.f};
  const float inv_norm = 0.08838834764831845f;  // 1/sqrt(128)

  const int ntiles = blockIdx.y + 1;  // causal: kv tiles 0..qtile
  for (int t = 0; t < ntiles; ++t) {
    const int kv0 = t * 64;
    __syncthreads();
    {
      // stage K tile [64 kv][128 d]
      const int g16 = tid & 15, rowk = tid >> 4;
#pragma unroll
      for (int p = 0; p < 4; ++p) {
        int r2 = rowk + p * 16;
        u16x8 vk = *(const u16x8*)&k_bf[(long long)(h * SEQL + kv0 + r2) * HDIM + g16 * 8];
        *(u16x8*)((char*)Ks + r2 * 256 + ((g16 * 16) ^ ((r2 & 7) << 4))) = vk;
      }
      // stage V^T tile [128 d][64 kv]
      const int g8 = tid & 7, rowv = tid >> 3;
#pragma unroll
      for (int p = 0; p < 4; ++p) {
        int r2 = rowv + p * 32;
        u16x8 vv = *(const u16x8*)&v_t[(long long)(h * HDIM + r2) * SEQL + kv0 + g8 * 8];
        *(u16x8*)((char*)Vs + r2 * 128 + ((g8 * 16) ^ ((r2 & 7) << 4))) = vv;
      }
    }
    __syncthreads();

    // QK^T: 16x64 scores per wave
    f32x4 sacc[4] = {};
#pragma unroll
    for (int kk = 0; kk < 4; ++kk) {
      const int colb = kk * 64 + (l >> 4) * 16;
#pragma unroll
      for (int n = 0; n < 4; ++n) {
        int row = n * 16 + (l & 15);
        bf16x8 kf = *(const bf16x8*)((char*)Ks + row * 256 + (colb ^ ((row & 7) << 4)));
        sacc[n] = __builtin_amdgcn_mfma_f32_16x16x32_bf16(qf[kk], kf, sacc[n], 0, 0, 0);
      }
    }

    // alibi + scale + causal mask
    float sc[4][4];  // [n][r]
#pragma unroll
    for (int n = 0; n < 4; ++n) {
      const int kv = kv0 + n * 16 + (l & 15);
      const float al = Al[kv];
#pragma unroll
      for (int r = 0; r < 4; ++r) {
        const int qrow = qw + (l >> 4) * 4 + r;
        float v = al + inv_norm * sacc[n][r];
        sc[n][r] = (kv > qrow) ? -__builtin_inff() : v;
      }
    }

    // online softmax per q row (16 lanes hold one row's scores, 4 cols each)
#pragma unroll
    for (int r = 0; r < 4; ++r) {
      float m0 = fmaxf(fmaxf(sc[0][r], sc[1][r]), fmaxf(sc[2][r], sc[3][r]));
      m0 = fmaxf(m0, __shfl_xor(m0, 1, 64));
      m0 = fmaxf(m0, __shfl_xor(m0, 2, 64));
      m0 = fmaxf(m0, __shfl_xor(m0, 4, 64));
      m0 = fmaxf(m0, __shfl_xor(m0, 8, 64));
      const float mnew = fmaxf(mrun[r], m0);
      float p0 = 0.f;
#pragma unroll
      for (int n = 0; n < 4; ++n) {
        const float pv = __expf(sc[n][r] - mnew);
        sc[n][r] = pv;
        p0 += pv;
      }
      p0 += __shfl_xor(p0, 1, 64);
      p0 += __shfl_xor(p0, 2, 64);
      p0 += __shfl_xor(p0, 4, 64);
      p0 += __shfl_xor(p0, 8, 64);
      const float scale = __expf(mrun[r] - mnew);  // 0 on first tile (mrun=-inf)
      mrun[r] = mnew;
      lrun[r] = lrun[r] * scale + p0;
#pragma unroll
      for (int n2 = 0; n2 < 8; ++n2) oacc[n2][r] *= scale;
    }

    // P -> per-wave LDS (bf16, swizzled), then re-read as MFMA A fragments
#pragma unroll
    for (int n = 0; n < 4; ++n)
#pragma unroll
      for (int r = 0; r < 4; ++r) {
        const int row = (l >> 4) * 4 + r;
        const int colp = n * 16 + (l & 15);
        *(unsigned short*)((char*)Ps[w] + row * 128 + ((colp * 2) ^ ((row & 7) << 4))) =
            f2bf(sc[n][r]);
      }
    __threadfence_block();  // order per-wave LDS write->read
    bf16x8 pf[2];
#pragma unroll
    for (int kk2 = 0; kk2 < 2; ++kk2) {
      const int row = l & 15;
      const int colb = kk2 * 64 + (l >> 4) * 16;
      pf[kk2] = *(const bf16x8*)((char*)Ps[w] + row * 128 + (colb ^ ((row & 7) << 4)));
    }

    // PV: ctx[16][128] += P[16][64] @ V[64][128]
#pragma unroll
    for (int n2 = 0; n2 < 8; ++n2) {
#pragma unroll
      for (int kk2 = 0; kk2 < 2; ++kk2) {
        const int row = n2 * 16 + (l & 15);  // d row in Vs
        const int colb = kk2 * 64 + (l >> 4) * 16;
        bf16x8 vf = *(const bf16x8*)((char*)Vs + row * 128 + (colb ^ ((row & 7) << 4)));
        oacc[n2] = __builtin_amdgcn_mfma_f32_16x16x32_bf16(pf[kk2], vf, oacc[n2], 0, 0, 0);
      }
    }
  }

  // write ctx as bf16 [s][H], col = h*128 + d
#pragma unroll
  for (int n2 = 0; n2 < 8; ++n2)
#pragma unroll
    for (int r = 0; r < 4; ++r) {
      const int qrow = qw + (l >> 4) * 4 + r;
      const int col = h * HDIM + n2 * 16 + (l & 15);
      ctx_bf[(long long)qrow * HIDN + col] = f2bf(oacc[n2][r] / lrun[r]);
    }
}

extern "C" void kernel_launch(void* const* d_in, const int* in_sizes, int n_in,
                              void* d_out, int out_size, void* d_ws, size_t ws_size,
                              hipStream_t stream) {
  const float* hidden = (const float*)d_in[0];
  const float* residual = (const float*)d_in[1];
  const float* alibi = (const float*)d_in[2];
  // d_in[3]: attention_mask (bool) — causal mask is computed analytically
  const float* Wqkv = (const float*)d_in[4];
  const float* bqkv = (const float*)d_in[5];
  const float* Wd = (const float*)d_in[6];
  const float* bd = (const float*)d_in[7];
  float* out = (float*)d_out;

  char* ws = (char*)d_ws;
  const size_t MB16 = 16777216;
  unsigned short* q_bf = (unsigned short*)(ws);
  unsigned short* k_bf = (unsigned short*)(ws + MB16);
  unsigned short* v_t = (unsigned short*)(ws + 2 * MB16);
  unsigned short* hid_bf = (unsigned short*)(ws + 3 * MB16);
  unsigned short* wqkv_bf = (unsigned short*)(ws + 4 * MB16);  // 96 MiB
  unsigned short* wd_bf = (unsigned short*)(ws + 4 * MB16);    // reuse after QKV GEMM
  unsigned short* ctx_bf = (unsigned short*)(ws + 4 * MB16 + 33554432);

  // 1. convert inputs to bf16
  cvt_f32_bf16<<<4096, 256, 0, stream>>>(hidden, hid_bf, (long long)SEQL * HIDN);
  cvt_f32_bf16<<<24576, 256, 0, stream>>>(Wqkv, wqkv_bf, (long long)H3 * HIDN);

  // 2. QKV projection with interleaved-scatter epilogue
  gemm_nt<0><<<dim3(H3 / 128, SEQL / 128), 256, 0, stream>>>(
      hid_bf, wqkv_bf, SEQL, H3, HIDN, bqkv, nullptr, nullptr, q_bf, k_bf, v_t);

  // 3. convert Wd (reuses Wqkv region — stream-ordered after QKV GEMM)
  cvt_f32_bf16<<<8192, 256, 0, stream>>>(Wd, wd_bf, (long long)HIDN * HIDN);

  // 4. flash attention (alibi + causal)
  attn_fwd<<<dim3(NHEAD, SEQL / 64), 256, 0, stream>>>(q_bf, k_bf, v_t, alibi, ctx_bf);

  // 5. output projection + bias + residual (fp32 out)
  gemm_nt<1><<<dim3(HIDN / 128, SEQL / 128), 256, 0, stream>>>(
      ctx_bf, wd_bf, SEQL, HIDN, HIDN, bd, residual, out, nullptr, nullptr, nullptr);
}

// Round 2
// 522.571 us; speedup vs baseline: 1.0551x; 1.0551x over previous
//
#include <hip/hip_runtime.h>

// BLOOM attention block on MI355X (gfx950).
// All GEMM-shaped compute in bf16 MFMA (16x16x32) with fp32 accumulation.
// Staging via global_load_lds width=16 (linear LDS dest + pre-swizzled global
// source chunk; read side applies the same XOR involution).
// Workspace layout (requires ws_size >= 160 MiB):
//   [0)        q_bf   [32][2048][128] bf16   16 MiB
//   [16M)      k_bf   [32][2048][128] bf16   16 MiB
//   [32M)      v_t    [32][128][2048] bf16   16 MiB  (V transposed: [head][d][s])
//   [48M)      hid_bf [2048][4096]    bf16   16 MiB
//   [64M)      wbig:  Wqkv_bf [12288][4096] (96 MiB), later reused as
//              Wd_bf [4096][4096] (32 MiB) + ctx_bf [2048][4096] (16 MiB)

#define SEQL 2048
#define HIDN 4096
#define NHEAD 32
#define HDIM 128
#define H3 12288

typedef __bf16 bf16x8 __attribute__((ext_vector_type(8)));
typedef float f32x4 __attribute__((ext_vector_type(4)));
typedef unsigned short u16x8 __attribute__((ext_vector_type(8)));

__device__ __forceinline__ unsigned short f2bf(float f) {
  union { float f; unsigned u; } v; v.f = f;
  return (unsigned short)((v.u + 0x7FFFu + ((v.u >> 16) & 1u)) >> 16);
}

__device__ __forceinline__ void gload_lds16(const void* g, void* l) {
  __builtin_amdgcn_global_load_lds(
      (const __attribute__((address_space(1))) void*)g,
      (__attribute__((address_space(3))) void*)l, 16, 0, 0);
}

__global__ __launch_bounds__(256) void cvt_f32_bf16(
    const float* __restrict__ in, unsigned short* __restrict__ out, long long n) {
  long long i = ((long long)blockIdx.x * blockDim.x + threadIdx.x) * 8;
  long long stride = (long long)gridDim.x * blockDim.x * 8;
  for (; i < n; i += stride) {
    float4 a = *(const float4*)(in + i);
    float4 b = *(const float4*)(in + i + 4);
    u16x8 o;
    o[0] = f2bf(a.x); o[1] = f2bf(a.y); o[2] = f2bf(a.z); o[3] = f2bf(a.w);
    o[4] = f2bf(b.x); o[5] = f2bf(b.y); o[6] = f2bf(b.z); o[7] = f2bf(b.w);
    *(u16x8*)(out + i) = o;
  }
}

// C[M,N] = A[M,K] * B[N,K]^T (+ epilogue). A,B bf16 (ushort bits).
// 128x128 tile, BK=64, 4 waves (2x2 of 64x64), 16x16x32 MFMA, 4x4 frags/wave.
// LDS tiles hold swizzled data: LDS[row][chunk j] = G[row][j ^ (row&7)]
// (16B chunks); reads apply byte ^= ((row&7)<<4).
// Grid: x = M/128 (fast; consecutive blocks share a B-panel), y = N/128.
// EPI==0: QKV scatter epilogue (bias + write q/k/v_t as bf16).
// EPI==1: out = acc + bias[col] + residual[row*N+col], fp32.
template <int EPI>
__global__ __launch_bounds__(256) void gemm_nt(
    const unsigned short* __restrict__ A, const unsigned short* __restrict__ B,
    int M, int N, int K,
    const float* __restrict__ bias, const float* __restrict__ residual,
    float* __restrict__ outf,
    unsigned short* __restrict__ q_bf, unsigned short* __restrict__ k_bf,
    unsigned short* __restrict__ v_t) {
  __shared__ unsigned short As[128 * 64];  // 16 KiB
  __shared__ unsigned short Bs[128 * 64];  // 16 KiB

  const int tid = threadIdx.x;
  const int l = tid & 63;
  const int w = tid >> 6;
  const int wr = (w >> 1) * 64;   // wave row offset in tile
  const int wc = (w & 1) * 64;    // wave col offset in tile
  const int tm0 = blockIdx.x * 128;
  const int tn0 = blockIdx.y * 128;

  // global_load_lds staging geometry: each wave-issue covers one 1024B LDS
  // chunk = 8 rows x 128B. lane l -> row-in-chunk l>>3, 16B-chunk l&7.
  // Source chunk pre-swizzled: (l&7) ^ (row&7), and row&7 == l>>3.
  const int lr = l >> 3;          // 0..7
  const int lc = (l & 7) ^ lr;    // swizzled 16B source chunk

  f32x4 acc[4][4] = {};

  for (int kt = 0; kt < K; kt += 64) {
    __syncthreads();
#pragma unroll
    for (int i = 0; i < 4; ++i) {
      const int row = w * 32 + i * 8 + lr;
      gload_lds16(&A[(long long)(tm0 + row) * K + kt + lc * 8],
                  (char*)As + (w * 4 + i) * 1024);
      gload_lds16(&B[(long long)(tn0 + row) * K + kt + lc * 8],
                  (char*)Bs + (w * 4 + i) * 1024);
    }
    __syncthreads();
#pragma unroll
    for (int kk = 0; kk < 2; ++kk) {
      const int colb = kk * 64 + (l >> 4) * 16;  // byte offset in row
      bf16x8 af[4], bfr[4];
#pragma unroll
      for (int m = 0; m < 4; ++m) {
        int row = wr + m * 16 + (l & 15);
        af[m] = *(const bf16x8*)((char*)As + row * 128 + (colb ^ ((row & 7) << 4)));
      }
#pragma unroll
      for (int n = 0; n < 4; ++n) {
        int row = wc + n * 16 + (l & 15);
        bfr[n] = *(const bf16x8*)((char*)Bs + row * 128 + (colb ^ ((row & 7) << 4)));
      }
#pragma unroll
      for (int m = 0; m < 4; ++m)
#pragma unroll
        for (int n = 0; n < 4; ++n)
          acc[m][n] = __builtin_amdgcn_mfma_f32_16x16x32_bf16(af[m], bfr[n], acc[m][n], 0, 0, 0);
    }
  }

  // Epilogue. D layout: col = lane&15, row = (lane>>4)*4 + reg (m89-verified).
#pragma unroll
  for (int m = 0; m < 4; ++m) {
#pragma unroll
    for (int n = 0; n < 4; ++n) {
      const int col = tn0 + wc + n * 16 + (l & 15);
      const float bv = bias[col];
#pragma unroll
      for (int r = 0; r < 4; ++r) {
        const int rowg = tm0 + wr + m * 16 + (l >> 4) * 4 + r;
        float v = acc[m][n][r] + bv;
        if (EPI == 0) {
          // fused[s, head*384 + which*128 + d]
          const int head = col / 384;
          const int rem = col - head * 384;
          const int which = rem >> 7;
          const int d = rem & 127;
          const unsigned short bv16 = f2bf(v);
          if (which == 0)
            q_bf[(long long)(head * SEQL + rowg) * HDIM + d] = bv16;
          else if (which == 1)
            k_bf[(long long)(head * SEQL + rowg) * HDIM + d] = bv16;
          else
            v_t[(long long)(head * HDIM + d) * SEQL + rowg] = bv16;
        } else {
          const long long idx = (long long)rowg * N + col;
          outf[idx] = v + residual[idx];
        }
      }
    }
  }
}

// Flash attention with alibi + causal mask.
// Block: one head x 64 q rows. 4 waves, each owns 16 q rows.
// KV tiles of 64. K staged [64][128], V^T staged [128][64], both XOR-swizzled
// via pre-swizzled global_load_lds source chunks.
__global__ __launch_bounds__(256) void attn_fwd(
    const unsigned short* __restrict__ q_bf, const unsigned short* __restrict__ k_bf,
    const unsigned short* __restrict__ v_t, const float* __restrict__ alibi,
    unsigned short* __restrict__ ctx_bf) {
  __shared__ unsigned short Ks[64 * 128];   // 16 KiB (rows = kv, 256B/row)
  __shared__ unsigned short Vs[128 * 64];   // 16 KiB (rows = d, 128B/row)
  __shared__ unsigned short Ps[4][16 * 64]; // 8 KiB  (per-wave P tile)
  __shared__ float Al[SEQL];                // 8 KiB  (alibi row for this head)

  const int tid = threadIdx.x;
  const int l = tid & 63;
  const int w = tid >> 6;
  const int h = blockIdx.x;
  const int qt = blockIdx.y * 64;
  const int qw = qt + w * 16;  // this wave's q-row base

  for (int i = tid; i < SEQL; i += 256) Al[i] = alibi[h * SEQL + i];

  // Q fragments in registers: lane l holds row qw+(l&15), cols kk*32+(l>>4)*8..+7
  bf16x8 qf[4];
  {
    const unsigned short* qp =
        &q_bf[(long long)(h * SEQL + qw + (l & 15)) * HDIM + (l >> 4) * 8];
#pragma unroll
    for (int kk = 0; kk < 4; ++kk) qf[kk] = *(const bf16x8*)(qp + kk * 32);
  }

  f32x4 oacc[8] = {};
  float mrun[4] = {-__builtin_inff(), -__builtin_inff(), -__builtin_inff(), -__builtin_inff()};
  float lrun[4] = {0.f, 0.f, 0.f, 0.f};
  const float inv_norm = 0.08838834764831845f;  // 1/sqrt(128)

  // K staging: chunk c = w*4+i covers rows c*4..+3 (256B rows).
  //   lane l: row-in-chunk l>>4, 16B-chunk l&15; row&7 = (i&1)*4 + (l>>4).
  // V staging: chunk c = w*4+i covers rows c*8..+7 (128B rows).
  //   lane l: row-in-chunk l>>3, chunk l&7; row&7 = l>>3.
  const int kR = l >> 4, kC = l & 15;
  const int vR = l >> 3, vC = (l & 7) ^ vR;

  const int ntiles = blockIdx.y + 1;  // causal: kv tiles 0..qtile
  for (int t = 0; t < ntiles; ++t) {
    const int kv0 = t * 64;
    __syncthreads();
#pragma unroll
    for (int i = 0; i < 4; ++i) {
      const int krow = w * 16 + i * 4 + kR;
      const int ksrc = kC ^ ((i & 1) * 4 + kR);
      gload_lds16(&k_bf[(long long)(h * SEQL + kv0 + krow) * HDIM + ksrc * 8],
                  (char*)Ks + (w * 4 + i) * 1024);
      const int vrow = w * 32 + i * 8 + vR;
      gload_lds16(&v_t[(long long)(h * HDIM + vrow) * SEQL + kv0 + vC * 8],
                  (char*)Vs + (w * 4 + i) * 1024);
    }
    __syncthreads();

    // QK^T: 16x64 scores per wave
    f32x4 sacc[4] = {};
#pragma unroll
    for (int kk = 0; kk < 4; ++kk) {
      const int colb = kk * 64 + (l >> 4) * 16;
#pragma unroll
      for (int n = 0; n < 4; ++n) {
        int row = n * 16 + (l & 15);
        bf16x8 kf = *(const bf16x8*)((char*)Ks + row * 256 + (colb ^ ((row & 7) << 4)));
        sacc[n] = __builtin_amdgcn_mfma_f32_16x16x32_bf16(qf[kk], kf, sacc[n], 0, 0, 0);
      }
    }

    // alibi + scale + causal mask
    float sc[4][4];  // [n][r]
#pragma unroll
    for (int n = 0; n < 4; ++n) {
      const int kv = kv0 + n * 16 + (l & 15);
      const float al = Al[kv];
#pragma unroll
      for (int r = 0; r < 4; ++r) {
        const int qrow = qw + (l >> 4) * 4 + r;
        float v = al + inv_norm * sacc[n][r];
        sc[n][r] = (kv > qrow) ? -__builtin_inff() : v;
      }
    }

    // online softmax per q row (16 lanes hold one row's scores, 4 cols each)
#pragma unroll
    for (int r = 0; r < 4; ++r) {
      float m0 = fmaxf(fmaxf(sc[0][r], sc[1][r]), fmaxf(sc[2][r], sc[3][r]));
      m0 = fmaxf(m0, __shfl_xor(m0, 1, 64));
      m0 = fmaxf(m0, __shfl_xor(m0, 2, 64));
      m0 = fmaxf(m0, __shfl_xor(m0, 4, 64));
      m0 = fmaxf(m0, __shfl_xor(m0, 8, 64));
      const float mnew = fmaxf(mrun[r], m0);
      float p0 = 0.f;
#pragma unroll
      for (int n = 0; n < 4; ++n) {
        const float pv = __expf(sc[n][r] - mnew);
        sc[n][r] = pv;
        p0 += pv;
      }
      p0 += __shfl_xor(p0, 1, 64);
      p0 += __shfl_xor(p0, 2, 64);
      p0 += __shfl_xor(p0, 4, 64);
      p0 += __shfl_xor(p0, 8, 64);
      const float scale = __expf(mrun[r] - mnew);  // 0 on first tile (mrun=-inf)
      mrun[r] = mnew;
      lrun[r] = lrun[r] * scale + p0;
#pragma unroll
      for (int n2 = 0; n2 < 8; ++n2) oacc[n2][r] *= scale;
    }

    // P -> per-wave LDS (bf16, swizzled), then re-read as MFMA A fragments
#pragma unroll
    for (int n = 0; n < 4; ++n)
#pragma unroll
      for (int r = 0; r < 4; ++r) {
        const int row = (l >> 4) * 4 + r;
        const int colp = n * 16 + (l & 15);
        *(unsigned short*)((char*)Ps[w] + row * 128 + ((colp * 2) ^ ((row & 7) << 4))) =
            f2bf(sc[n][r]);
      }
    __threadfence_block();  // order per-wave LDS write->read
    bf16x8 pf[2];
#pragma unroll
    for (int kk2 = 0; kk2 < 2; ++kk2) {
      const int row = l & 15;
      const int colb = kk2 * 64 + (l >> 4) * 16;
      pf[kk2] = *(const bf16x8*)((char*)Ps[w] + row * 128 + (colb ^ ((row & 7) << 4)));
    }

    // PV: ctx[16][128] += P[16][64] @ V[64][128]
#pragma unroll
    for (int n2 = 0; n2 < 8; ++n2) {
#pragma unroll
      for (int kk2 = 0; kk2 < 2; ++kk2) {
        const int row = n2 * 16 + (l & 15);  // d row in Vs
        const int colb = kk2 * 64 + (l >> 4) * 16;
        bf16x8 vf = *(const bf16x8*)((char*)Vs + row * 128 + (colb ^ ((row & 7) << 4)));
        oacc[n2] = __builtin_amdgcn_mfma_f32_16x16x32_bf16(pf[kk2], vf, oacc[n2], 0, 0, 0);
      }
    }
  }

  // write ctx as bf16 [s][H], col = h*128 + d
#pragma unroll
  for (int n2 = 0; n2 < 8; ++n2)
#pragma unroll
    for (int r = 0; r < 4; ++r) {
      const int qrow = qw + (l >> 4) * 4 + r;
      const int col = h * HDIM + n2 * 16 + (l & 15);
      ctx_bf[(long long)qrow * HIDN + col] = f2bf(oacc[n2][r] / lrun[r]);
    }
}

extern "C" void kernel_launch(void* const* d_in, const int* in_sizes, int n_in,
                              void* d_out, int out_size, void* d_ws, size_t ws_size,
                              hipStream_t stream) {
  const float* hidden = (const float*)d_in[0];
  const float* residual = (const float*)d_in[1];
  const float* alibi = (const float*)d_in[2];
  // d_in[3]: attention_mask (bool) — causal mask is computed analytically
  const float* Wqkv = (const float*)d_in[4];
  const float* bqkv = (const float*)d_in[5];
  const float* Wd = (const float*)d_in[6];
  const float* bd = (const float*)d_in[7];
  float* out = (float*)d_out;

  char* ws = (char*)d_ws;
  const size_t MB16 = 16777216;
  unsigned short* q_bf = (unsigned short*)(ws);
  unsigned short* k_bf = (unsigned short*)(ws + MB16);
  unsigned short* v_t = (unsigned short*)(ws + 2 * MB16);
  unsigned short* hid_bf = (unsigned short*)(ws + 3 * MB16);
  unsigned short* wqkv_bf = (unsigned short*)(ws + 4 * MB16);  // 96 MiB
  unsigned short* wd_bf = (unsigned short*)(ws + 4 * MB16);    // reuse after QKV GEMM
  unsigned short* ctx_bf = (unsigned short*)(ws + 4 * MB16 + 33554432);

  // 1. convert inputs to bf16
  cvt_f32_bf16<<<4096, 256, 0, stream>>>(hidden, hid_bf, (long long)SEQL * HIDN);
  cvt_f32_bf16<<<24576, 256, 0, stream>>>(Wqkv, wqkv_bf, (long long)H3 * HIDN);

  // 2. QKV projection with interleaved-scatter epilogue
  gemm_nt<0><<<dim3(SEQL / 128, H3 / 128), 256, 0, stream>>>(
      hid_bf, wqkv_bf, SEQL, H3, HIDN, bqkv, nullptr, nullptr, q_bf, k_bf, v_t);

  // 3. convert Wd (reuses Wqkv region — stream-ordered after QKV GEMM)
  cvt_f32_bf16<<<8192, 256, 0, stream>>>(Wd, wd_bf, (long long)HIDN * HIDN);

  // 4. flash attention (alibi + causal)
  attn_fwd<<<dim3(NHEAD, SEQL / 64), 256, 0, stream>>>(q_bf, k_bf, v_t, alibi, ctx_bf);

  // 5. output projection + bias + residual (fp32 out)
  gemm_nt<1><<<dim3(SEQL / 128, HIDN / 128), 256, 0, stream>>>(
      ctx_bf, wd_bf, SEQL, HIDN, HIDN, bd, residual, out, nullptr, nullptr, nullptr);
}